// Round 1
// baseline (402.689 us; speedup 1.0000x reference)
//
#include <hip/hip_runtime.h>
#include <math.h>

// Quantum circuit collapses analytically:
//   z_w = cos(q_params[w]) * cos(features[w])   (RZ layer is pure phase -> no-op on probs)
//   q_out = [z0, z0*z1, z0*z1*z2, z0*z1*z2*z3]  (CNOT chain = parity of independent bits)
// Then MLP 4->64 (relu) -> 4, batchnorm over batch.
//
// Restructured vs previous version:
//   - 6 threads per image (one pooled row each, 6 contiguous float4s = 96B/thread)
//     instead of 1 thread walking 36 scattered loads with 5184B inter-lane stride.
//   - blockDim 384, 64 images/block -> 1024 blocks, 6144 waves (24 waves/CU) vs 1024
//     waves (1/SIMD) before. Latency now hidden by TLP.
//   - LDS reduction of row partials -> features -> z; 64 threads/block run the MLP.

#define IMGS 64
#define TPB  384

__global__ void k_init(float* acc) {
    if (threadIdx.x < 8) acc[threadIdx.x] = 0.0f;
}

__global__ __launch_bounds__(TPB) void k_main(
    const float* __restrict__ x,
    const float* __restrict__ qp,
    const float* __restrict__ W1,
    const float* __restrict__ b1,
    const float* __restrict__ W2,
    const float* __restrict__ b2,
    float* __restrict__ logits,
    float* __restrict__ acc,
    int B)
{
    __shared__ float sW1[256];     // [j][w], row-major 64x4
    __shared__ float sW2t[256];    // [j][k] (transpose of W2 4x64)
    __shared__ float sb1[64];
    __shared__ float scqp[4];      // cos(q_params[w])
    __shared__ float part[4][TPB]; // per-(image,row) partial col sums, [w][tid]
    __shared__ float zbuf[IMGS * 4];

    const int tid = threadIdx.x;
    if (tid < 256) {
        sW1[tid]  = W1[tid];
        sW2t[tid] = W2[(tid & 3) * 64 + (tid >> 2)];
    }
    if (tid < 64) sb1[tid] = b1[tid];
    if (tid < 4)  scqp[tid] = cosf(qp[tid]);

    // ---- phase 1: pooled-row partial sums. thread = (image, row r in 0..5) ----
    const int ib = tid / 6;          // 0..63  local image
    const int r  = tid - ib * 6;     // 0..5   row
    const int bg1 = blockIdx.x * IMGS + ib;
    float c0 = 0.f, c1 = 0.f, c2 = 0.f, c3 = 0.f;
    if (bg1 < B) {
        const float4* row = (const float4*)(x + (size_t)bg1 * 1296 + r * 36);
        float4 v0 = row[0], v1 = row[1], v2 = row[2];
        float4 v3 = row[3], v4 = row[4], v5 = row[5];
        c0 = v0.x + v0.y + v0.z + v0.w + v1.x + v1.y;  // cols 0..5
        c1 = v1.z + v1.w + v2.x + v2.y + v2.z + v2.w;  // cols 6..11
        c2 = v3.x + v3.y + v3.z + v3.w + v4.x + v4.y;  // cols 12..17
        c3 = v4.z + v4.w + v5.x + v5.y + v5.z + v5.w;  // cols 18..23
    }
    part[0][tid] = c0; part[1][tid] = c1; part[2][tid] = c2; part[3][tid] = c3;
    __syncthreads();

    // ---- phase 2: 256 threads = 64 images x 4 features -> z values ----
    if (tid < 256) {
        const int i = tid >> 2, w = tid & 3;
        const int base = i * 6;
        float f = part[w][base] + part[w][base + 1] + part[w][base + 2]
                + part[w][base + 3] + part[w][base + 4] + part[w][base + 5];
        zbuf[tid] = scqp[w] * cosf(f * (1.0f / 36.0f));  // zbuf[i*4+w] == zbuf[tid]
    }
    __syncthreads();

    // ---- phase 3: 64 threads run the MLP for their image ----
    if (tid < IMGS) {
        const int bg = blockIdx.x * IMGS + tid;
        float4 z = ((const float4*)zbuf)[tid];
        float q0 = z.x;
        float q1 = q0 * z.y;
        float q2 = q1 * z.z;
        float q3 = q2 * z.w;

        float l0 = b2[0], l1 = b2[1], l2 = b2[2], l3 = b2[3];
        #pragma unroll 8
        for (int j = 0; j < 64; ++j) {
            float h = sb1[j];
            h = fmaf(sW1[4 * j + 0], q0, h);
            h = fmaf(sW1[4 * j + 1], q1, h);
            h = fmaf(sW1[4 * j + 2], q2, h);
            h = fmaxf(fmaf(sW1[4 * j + 3], q3, h), 0.0f);
            l0 = fmaf(sW2t[4 * j + 0], h, l0);
            l1 = fmaf(sW2t[4 * j + 1], h, l1);
            l2 = fmaf(sW2t[4 * j + 2], h, l2);
            l3 = fmaf(sW2t[4 * j + 3], h, l3);
        }
        if (bg < B) {
            ((float4*)logits)[bg] = make_float4(l0, l1, l2, l3);
        } else {
            l0 = l1 = l2 = l3 = 0.0f;
        }

        // in-wave butterfly reduction (all values live in wave 0 only)
        float v[8] = {l0, l1, l2, l3, l0 * l0, l1 * l1, l2 * l2, l3 * l3};
        #pragma unroll
        for (int off = 32; off >= 1; off >>= 1) {
            #pragma unroll
            for (int i = 0; i < 8; ++i) v[i] += __shfl_xor(v[i], off);
        }
        if (tid < 8) atomicAdd(&acc[tid], v[tid]);
    }
}

__global__ __launch_bounds__(256) void k_norm(
    const float* __restrict__ logits,
    const float* __restrict__ acc,
    const float* __restrict__ gamma,
    const float* __restrict__ beta,
    float* __restrict__ out,
    int B, float invB)
{
    __shared__ float sc[4], sh[4];
    if (threadIdx.x < 4) {
        const int k = threadIdx.x;
        float mu   = acc[k] * invB;
        float var  = acc[4 + k] * invB - mu * mu;
        float rstd = 1.0f / sqrtf(var + 1e-5f);
        float g = gamma[k] * rstd;
        sc[k] = g;
        sh[k] = beta[k] - mu * g;
    }
    __syncthreads();
    const int b = blockIdx.x * 256 + threadIdx.x;
    if (b >= B) return;
    float4 l = ((const float4*)logits)[b];
    float4 o;
    o.x = fmaf(sc[0], l.x, sh[0]);
    o.y = fmaf(sc[1], l.y, sh[1]);
    o.z = fmaf(sc[2], l.z, sh[2]);
    o.w = fmaf(sc[3], l.w, sh[3]);
    ((float4*)out)[b] = o;
}

extern "C" void kernel_launch(void* const* d_in, const int* in_sizes, int n_in,
                              void* d_out, int out_size, void* d_ws, size_t ws_size,
                              hipStream_t stream) {
    const float* x     = (const float*)d_in[0];
    const float* qp    = (const float*)d_in[1];
    const float* W1    = (const float*)d_in[2];
    const float* b1    = (const float*)d_in[3];
    const float* W2    = (const float*)d_in[4];
    const float* b2    = (const float*)d_in[5];
    const float* gamma = (const float*)d_in[6];
    const float* beta  = (const float*)d_in[7];
    float* out = (float*)d_out;

    const int B = in_sizes[0] / 1296;           // 65536
    float* acc    = (float*)d_ws;               // 8 floats: sum[4], sumsq[4]
    float* logits = (float*)d_ws + 64;          // B*4 floats, 256B offset keeps float4 alignment

    const int nb_main = (B + IMGS - 1) / IMGS;  // 1024 blocks x 384 threads
    const int nb_norm = (B + 255) / 256;
    hipLaunchKernelGGL(k_init, dim3(1), dim3(64), 0, stream, acc);
    hipLaunchKernelGGL(k_main, dim3(nb_main), dim3(TPB), 0, stream,
                       x, qp, W1, b1, W2, b2, logits, acc, B);
    hipLaunchKernelGGL(k_norm, dim3(nb_norm), dim3(256), 0, stream,
                       logits, acc, gamma, beta, out, B, 1.0f / (float)B);
}